// Round 4
// baseline (1646.153 us; speedup 1.0000x reference)
//
#include <hip/hip_runtime.h>
#include <math.h>

#define Hh 256
#define Ww 256
#define HW 65536
#define Bn 4
#define Cdim 60
#define Ce 120
#define NPIX (Bn*HW)

typedef const float* fp;

// ---------------- LFE stage 1: y1 = gelu(conv1x1(shift(src), w0, b0)) ----------------
// Weights read with wave-uniform indices -> compiler emits scalar (SGPR) loads; no LDS.
__global__ __launch_bounds__(256) void k_lfe1(const float* __restrict__ X, float* __restrict__ Y1,
                                              fp w0, fp b0){
  int tid = threadIdx.x;
  int p = blockIdx.x*256 + tid;
  int b = p >> 16; int hw = p & 65535; int h = hw >> 8; int w = hw & 255;
  const float* Xb = X + (size_t)b*(Cdim*HW);
  float xs[Cdim];
  #pragma unroll
  for (int c = 0; c < Cdim; c++){
    int grp = c / 12;
    int hh = h, ww = w; bool ok = true;
    if (grp == 0){ ww = w+1; ok = (ww < Ww); }
    else if (grp == 1){ ww = w-1; ok = (ww >= 0); }
    else if (grp == 2){ hh = h+1; ok = (hh < Hh); }
    else if (grp == 3){ hh = h-1; ok = (hh >= 0); }
    xs[c] = ok ? Xb[c*HW + hh*Ww + ww] : 0.f;
  }
  float* Yb = Y1 + (size_t)b*(Ce*HW) + h*Ww + w;
  #pragma unroll 2
  for (int o = 0; o < Ce; o++){
    float acc = b0[o];
    #pragma unroll
    for (int c = 0; c < Cdim; c++)
      acc += w0[o*Cdim + c] * xs[c];
    float g = 0.5f*acc*(1.f + erff(acc*0.70710678118654752f)); // exact gelu
    Yb[o*HW] = g;
  }
}

// ---------------- LFE stage 2: X = conv1x1(shift(y1), w1, b1) + resid ----------------
// Cache all 120 shifted inputs in registers; weights in natural [c][e] order via scalar loads.
__global__ __launch_bounds__(256) void k_lfe2(const float* __restrict__ Y1,
                                              const float* __restrict__ R,
                                              float* __restrict__ X,
                                              fp w1, fp b1){
  int tid = threadIdx.x;
  int p = blockIdx.x*256 + tid;
  int b = p >> 16; int hw = p & 65535; int h = hw >> 8; int w = hw & 255;
  const float* Yb = Y1 + (size_t)b*(Ce*HW);
  float ys[Ce];
  #pragma unroll
  for (int e = 0; e < Ce; e++){
    int grp = e / 24;
    int hh = h, ww = w; bool ok = true;
    if (grp == 0){ ww = w+1; ok = (ww < Ww); }
    else if (grp == 1){ ww = w-1; ok = (ww >= 0); }
    else if (grp == 2){ hh = h+1; ok = (hh < Hh); }
    else if (grp == 3){ hh = h-1; ok = (hh >= 0); }
    ys[e] = ok ? Yb[e*HW + hh*Ww + ww] : 0.f;
  }
  const float* Rp = R + (size_t)b*(Cdim*HW) + hw;
  float* Xp = X + (size_t)b*(Cdim*HW) + hw;
  #pragma unroll 1
  for (int c = 0; c < Cdim; c++){
    float acc = b1[c];
    #pragma unroll
    for (int e = 0; e < Ce; e++)
      acc += w1[c*Ce + e] * ys[e];
    Xp[c*HW] = acc + Rp[c*HW];
  }
}

// ---------------- WSA stage 1: t = BN(conv1x1(x, pi_w, pi_b)) -- BN applied per out-ch ----------------
__global__ __launch_bounds__(256) void k_wsat(const float* __restrict__ X, float* __restrict__ T,
                                              fp piw, fp pib, fp g, fp bt, fp m, fp v){
  int tid = threadIdx.x;
  int p = blockIdx.x*256 + tid;
  int b = p >> 16; int hw = p & 65535;
  const float* Xb = X + (size_t)b*(Cdim*HW) + hw;
  float xs[Cdim];
  #pragma unroll
  for (int c = 0; c < Cdim; c++) xs[c] = Xb[c*HW];
  float* Tb = T + (size_t)b*(Cdim*HW) + hw;
  #pragma unroll 2
  for (int o = 0; o < Cdim; o++){
    float acc = 0.f;
    #pragma unroll
    for (int c = 0; c < Cdim; c++)
      acc += piw[o*Cdim + c] * xs[c];
    float scale = g[o] * rsqrtf(v[o] + 1e-5f);          // uniform scalar math
    float cns   = (pib[o] - m[o])*scale + bt[o];
    Tb[o*HW] = acc*scale + cns;
  }
}

// ---------------- WSA stage 2: windowed attention, 4x4 register tiles ----------------
// block = one window (b,i,j), 256 threads. LDS: 50 KB -> 3 blocks/CU.
__global__ __launch_bounds__(256) void k_attn(const float* __restrict__ T, float* __restrict__ Y,
                                              fp mw, fp mb){
  __shared__ __align__(16) float R1[64*68]; // sub[k*68+p], later V[tok*68+c]
  __shared__ __align__(16) float R2[64*68]; // mwT[k*68+c], later St[q*68+p]
  __shared__ __align__(16) float R3[60*64]; // Qt[c*64+tok]
  int tid = threadIdx.x;
  int blk = blockIdx.x;
  int b = blk >> 10; int ij = blk & 1023; int wi = ij >> 5; int wj = ij & 31;
  const float* Tb = T + (size_t)b*(Cdim*HW);

  // stage sub (stride-2 sampled, transposed, dup-edge): sub[k][p]
  for (int idx = tid; idx < Cdim*64; idx += 256){
    int k = idx >> 6, p = idx & 63;
    int u = p >> 3, vq = p & 7;
    int r  = wi*8 + 2*vq; if (r > 255) r -= 8;
    int cc = wj*8 + 2*u;  if (cc > 255) cc -= 8;
    R1[k*68 + p] = Tb[k*HW + r*Ww + cc];
  }
  // stage mwT[k][c] = mw[c][k]
  for (int idx = tid; idx < Cdim*Cdim; idx += 256){
    int k = idx / Cdim, c = idx - k*Cdim;
    R2[k*68 + c] = mw[c*Cdim + k];
  }
  __syncthreads();

  // qproj: q[p][c] = sum_k mwT[k][c]*sub[k][p] + mb[c]; 240 threads, 4x4 tiles
  if (tid < 240){
    int p0 = (tid & 15)*4, c0 = (tid >> 4)*4;
    float4 mb4 = *(const float4*)(mb + c0);
    float bias[4] = {mb4.x, mb4.y, mb4.z, mb4.w};
    float acc[4][4];
    #pragma unroll
    for (int ci = 0; ci < 4; ci++)
      #pragma unroll
      for (int pi = 0; pi < 4; pi++) acc[ci][pi] = bias[ci];
    #pragma unroll 4
    for (int k = 0; k < Cdim; k++){
      float4 A  = *(const float4*)(&R1[k*68 + p0]);
      float4 Bv = *(const float4*)(&R2[k*68 + c0]);
      float Af[4] = {A.x, A.y, A.z, A.w};
      float Bf[4] = {Bv.x, Bv.y, Bv.z, Bv.w};
      #pragma unroll
      for (int ci = 0; ci < 4; ci++)
        #pragma unroll
        for (int pi = 0; pi < 4; pi++)
          acc[ci][pi] += Bf[ci]*Af[pi];
    }
    #pragma unroll
    for (int ci = 0; ci < 4; ci++)
      *(float4*)(&R3[(c0+ci)*64 + p0]) = make_float4(acc[ci][0], acc[ci][1], acc[ci][2], acc[ci][3]);
  }
  __syncthreads();

  // stage V[tok][c] into R1 (sub dead), and scores into R2 (mwT dead)
  {
    int p = tid & 63; int cg = tid >> 6;
    int pr = p >> 3, pc = p & 7;
    const float* base = Tb + (wi*8+pr)*Ww + (wj*8+pc);
    #pragma unroll
    for (int t2 = 0; t2 < 15; t2++)
      R1[p*68 + cg*15 + t2] = base[(cg*15+t2)*HW];
  }
  if (tid < 64){
    R1[tid*68 + 60] = 0.f; R1[tid*68 + 61] = 0.f;
    R1[tid*68 + 62] = 0.f; R1[tid*68 + 63] = 0.f;
  }
  // scores S[p][q] = <q_p, q_q>, stored transposed St[q][p]
  {
    int p0 = (tid & 15)*4, q0 = (tid >> 4)*4;
    float acc[4][4];
    #pragma unroll
    for (int qi = 0; qi < 4; qi++)
      #pragma unroll
      for (int pi = 0; pi < 4; pi++) acc[qi][pi] = 0.f;
    #pragma unroll 4
    for (int c = 0; c < Cdim; c++){
      float4 A  = *(const float4*)(&R3[c*64 + p0]);
      float4 Bv = *(const float4*)(&R3[c*64 + q0]);
      float Af[4] = {A.x, A.y, A.z, A.w};
      float Bf[4] = {Bv.x, Bv.y, Bv.z, Bv.w};
      #pragma unroll
      for (int qi = 0; qi < 4; qi++)
        #pragma unroll
        for (int pi = 0; pi < 4; pi++)
          acc[qi][pi] += Bf[qi]*Af[pi];
    }
    __syncthreads();  // wait for everyone to finish reading R2 (mwT) -- and R1 V-stage done
    #pragma unroll
    for (int qi = 0; qi < 4; qi++)
      *(float4*)(&R2[(q0+qi)*68 + p0]) = make_float4(acc[qi][0], acc[qi][1], acc[qi][2], acc[qi][3]);
  }
  __syncthreads();

  // softmax over q for each row p (one lane per row)
  if (tid < 64){
    int p = tid;
    float mx = -1e30f;
    #pragma unroll
    for (int q = 0; q < 64; q++) mx = fmaxf(mx, R2[q*68 + p]);
    float sum = 0.f;
    #pragma unroll
    for (int q = 0; q < 64; q++){
      float e = __expf(R2[q*68 + p] - mx);
      R2[q*68 + p] = e; sum += e;
    }
    float inv = 1.f/sum;
    #pragma unroll
    for (int q = 0; q < 64; q++) R2[q*68 + p] *= inv;
  }
  __syncthreads();

  // PV: y[p][c] = sum_q atn[p][q] * V[q][c]; 4x4 tiles
  {
    int p0 = (tid & 15)*4, c0 = (tid >> 4)*4;
    float acc[4][4];
    #pragma unroll
    for (int ci = 0; ci < 4; ci++)
      #pragma unroll
      for (int pi = 0; pi < 4; pi++) acc[ci][pi] = 0.f;
    #pragma unroll 4
    for (int q = 0; q < 64; q++){
      float4 S4 = *(const float4*)(&R2[q*68 + p0]);
      float4 V4 = *(const float4*)(&R1[q*68 + c0]);
      float Sf[4] = {S4.x, S4.y, S4.z, S4.w};
      float Vf[4] = {V4.x, V4.y, V4.z, V4.w};
      #pragma unroll
      for (int ci = 0; ci < 4; ci++)
        #pragma unroll
        for (int pi = 0; pi < 4; pi++)
          acc[ci][pi] += Sf[pi]*Vf[ci];
    }
    float* Yb = Y + (size_t)b*(Cdim*HW);
    #pragma unroll
    for (int ci = 0; ci < 4; ci++){
      int c = c0 + ci;
      if (c < Cdim){
        #pragma unroll
        for (int pi = 0; pi < 4; pi++){
          int p = p0 + pi;
          Yb[c*HW + (wi*8 + (p>>3))*Ww + wj*8 + (p&7)] = acc[ci][pi];
        }
      }
    }
  }
}

// ---------------- WSA stage 3: X = conv1x1(y, po) + X (in place) ----------------
__global__ __launch_bounds__(256) void k_wsaout(const float* __restrict__ Y, float* __restrict__ X,
                                                fp pw, fp pb){
  int tid = threadIdx.x;
  int p = blockIdx.x*256 + tid;
  int b = p >> 16; int hw = p & 65535;
  const float* Yb = Y + (size_t)b*(Cdim*HW) + hw;
  float ys[Cdim];
  #pragma unroll
  for (int c = 0; c < Cdim; c++) ys[c] = Yb[c*HW];
  float* Xp = X + (size_t)b*(Cdim*HW) + hw;
  #pragma unroll 2
  for (int o = 0; o < Cdim; o++){
    float acc = pb[o];
    #pragma unroll
    for (int c = 0; c < Cdim; c++)
      acc += pw[o*Cdim + c] * ys[c];
    Xp[o*HW] = acc + Xp[o*HW];
  }
}

extern "C" void kernel_launch(void* const* d_in, const int* in_sizes, int n_in,
                              void* d_out, int out_size, void* d_ws, size_t ws_size,
                              hipStream_t stream){
  fp x      = (fp)d_in[0];
  fp lfe_w0 = (fp)d_in[1];
  fp lfe_b0 = (fp)d_in[2];
  fp lfe_w1 = (fp)d_in[3];
  fp lfe_b1 = (fp)d_in[4];
  fp pi_w   = (fp)d_in[5];
  fp pi_b   = (fp)d_in[6];
  fp bn_g   = (fp)d_in[7];
  fp bn_b   = (fp)d_in[8];
  fp bn_m   = (fp)d_in[9];
  fp bn_v   = (fp)d_in[10];
  fp mask_w = (fp)d_in[11];
  fp mask_b = (fp)d_in[12];
  fp po_w   = (fp)d_in[13];
  fp po_b   = (fp)d_in[14];

  const size_t XSZ = (size_t)Bn*Cdim*HW;     // 15,728,640 floats (63 MB)
  float* X  = (float*)d_out;                 // residual stream lives in d_out (fp32)
  float* Y1 = (float*)d_ws;                  // [0, 2*XSZ): 120-ch LFE intermediate
  float* T  = Y1;                            // [0, XSZ): t-tensor (Y1 dead by then)
  float* Yw = Y1 + XSZ;                      // [XSZ, 2*XSZ): attention output

  for (int d = 0; d < 2; d++){
    fp src = (d == 0) ? x : X;               // depth-0 reads the input directly
    k_lfe1  <<<NPIX/256, 256, 0, stream>>>(src, Y1, lfe_w0 + d*Ce*Cdim, lfe_b0 + d*Ce);
    k_lfe2  <<<NPIX/256, 256, 0, stream>>>(Y1, src, X, lfe_w1 + d*Ce*Cdim, lfe_b1 + d*Cdim);
    k_wsat  <<<NPIX/256, 256, 0, stream>>>(X, T, pi_w + d*Cdim*Cdim, pi_b + d*Cdim,
                                           bn_g + d*Cdim, bn_b + d*Cdim, bn_m + d*Cdim, bn_v + d*Cdim);
    k_attn  <<<Bn*32*32, 256, 0, stream>>>(T, Yw, mask_w + d*Cdim*Cdim, mask_b + d*Cdim);
    k_wsaout<<<NPIX/256, 256, 0, stream>>>(Yw, X, po_w + d*Cdim*Cdim, po_b + d*Cdim);
  }
}

// Round 5
// 1115.550 us; speedup vs baseline: 1.4756x; 1.4756x over previous
//
#include <hip/hip_runtime.h>
#include <math.h>

#define Hh 256
#define Ww 256
#define HW 65536
#define Bn 4
#define Cdim 60
#define Ce 120
#define NPIX (Bn*HW)

typedef const float* fp;

__device__ __forceinline__ float gelu_exact(float x){
  return 0.5f*x*(1.f + erff(x*0.70710678118654752f));
}

// decode 64-px tile id -> (b, h, tw). 1024 tiles/image (256 rows x 4 tiles).
__device__ __forceinline__ void tile_decode(int blk, int& b, int& h, int& tw){
  b = blk >> 10; int rem = blk & 1023; h = rem >> 2; tw = (rem & 3) << 6;
}

// ---------------- LFE stage 1: y1 = gelu(conv1x1(shift(src), w0, b0)) ----------------
// GEMM: M=64 px, N=120 out, K=60. 240 threads: 16 px-cols x 15 ch-groups, 8oc x 4px tiles.
__global__ __launch_bounds__(256) void k_lfe1(const float* __restrict__ X, float* __restrict__ Y1,
                                              fp w0, fp b0){
  __shared__ __align__(16) float A[60*64];     // shifted input [k][p]
  __shared__ __align__(16) float Wl[60*128];   // transposed weights [k][o]
  int tid = threadIdx.x;
  int b, h, tw; tile_decode(blockIdx.x, b, h, tw);
  const float* Xb = X + (size_t)b*(Cdim*HW);
  for (int idx = tid; idx < 60*64; idx += 256){
    int k = idx >> 6, p = idx & 63;
    int grp = k / 12;
    int hh = h, ww = tw + p; bool ok = true;
    if (grp == 0){ ww += 1; ok = (ww < Ww); }
    else if (grp == 1){ ww -= 1; ok = (ww >= 0); }
    else if (grp == 2){ hh = h+1; ok = (hh < Hh); }
    else if (grp == 3){ hh = h-1; ok = (hh >= 0); }
    A[idx] = ok ? Xb[k*HW + hh*Ww + ww] : 0.f;
  }
  for (int idx = tid; idx < 60*120; idx += 256){
    int k = idx / 120, o = idx - k*120;
    Wl[k*128 + o] = w0[o*Cdim + k];            // uncoalesced read (L1/L2-hot), conflict-free LDS write
  }
  __syncthreads();
  if (tid < 240){
    int p0 = (tid & 15)*4;
    int o0 = (tid >> 4)*8;
    float acc[8][4];
    #pragma unroll
    for (int oi = 0; oi < 8; oi++){
      float bb = b0[o0+oi];
      #pragma unroll
      for (int pi = 0; pi < 4; pi++) acc[oi][pi] = bb;
    }
    #pragma unroll 4
    for (int k = 0; k < 60; k++){
      float4 a4 = *(const float4*)(&A[k*64 + p0]);
      float4 wA = *(const float4*)(&Wl[k*128 + o0]);
      float4 wB = *(const float4*)(&Wl[k*128 + o0 + 4]);
      float av[4] = {a4.x,a4.y,a4.z,a4.w};
      float wv[8] = {wA.x,wA.y,wA.z,wA.w,wB.x,wB.y,wB.z,wB.w};
      #pragma unroll
      for (int oi = 0; oi < 8; oi++)
        #pragma unroll
        for (int pi = 0; pi < 4; pi++)
          acc[oi][pi] += wv[oi]*av[pi];
    }
    float* Yb = Y1 + (size_t)b*(Ce*HW) + h*Ww + tw + p0;
    #pragma unroll
    for (int oi = 0; oi < 8; oi++){
      float4 r;
      r.x = gelu_exact(acc[oi][0]); r.y = gelu_exact(acc[oi][1]);
      r.z = gelu_exact(acc[oi][2]); r.w = gelu_exact(acc[oi][3]);
      *(float4*)(Yb + (size_t)(o0+oi)*HW) = r;
    }
  }
}

// ---------------- LFE stage 2: X = conv1x1(shift(y1), w1, b1) + resid ----------------
// GEMM: M=64, N=60, K=120 (K staged in two halves to fit LDS). 240 threads, 4oc x 4px.
__global__ __launch_bounds__(256) void k_lfe2(const float* __restrict__ Y1,
                                              const float* __restrict__ R,
                                              float* __restrict__ X,
                                              fp w1, fp b1){
  __shared__ __align__(16) float A[60*64];     // half of shifted Y1 [k][p]
  __shared__ __align__(16) float Wl[120*64];   // transposed weights [e][c]
  int tid = threadIdx.x;
  int b, h, tw; tile_decode(blockIdx.x, b, h, tw);
  const float* Yb = Y1 + (size_t)b*(Ce*HW);
  for (int idx = tid; idx < 120*60; idx += 256){
    int e = idx / 60, c = idx - e*60;
    Wl[e*64 + c] = w1[c*Ce + e];
  }
  int p0 = (tid & 15)*4;
  int o0 = (tid >> 4)*4;
  float acc[4][4];
  #pragma unroll
  for (int oi = 0; oi < 4; oi++)
    #pragma unroll
    for (int pi = 0; pi < 4; pi++) acc[oi][pi] = 0.f;
  #pragma unroll 1
  for (int half = 0; half < 2; half++){
    __syncthreads();                            // W ready / previous GEMM half done
    for (int idx = tid; idx < 60*64; idx += 256){
      int k = idx >> 6, p = idx & 63;
      int e = half*60 + k;
      int grp = e / 24;
      int hh = h, ww = tw + p; bool ok = true;
      if (grp == 0){ ww += 1; ok = (ww < Ww); }
      else if (grp == 1){ ww -= 1; ok = (ww >= 0); }
      else if (grp == 2){ hh = h+1; ok = (hh < Hh); }
      else if (grp == 3){ hh = h-1; ok = (hh >= 0); }
      A[idx] = ok ? Yb[e*HW + hh*Ww + ww] : 0.f;
    }
    __syncthreads();
    if (tid < 240){
      #pragma unroll 4
      for (int k = 0; k < 60; k++){
        float4 a4 = *(const float4*)(&A[k*64 + p0]);
        float4 w4 = *(const float4*)(&Wl[(half*60+k)*64 + o0]);
        float av[4] = {a4.x,a4.y,a4.z,a4.w};
        float wv[4] = {w4.x,w4.y,w4.z,w4.w};
        #pragma unroll
        for (int oi = 0; oi < 4; oi++)
          #pragma unroll
          for (int pi = 0; pi < 4; pi++)
            acc[oi][pi] += wv[oi]*av[pi];
      }
    }
  }
  if (tid < 240){
    const float* Rp = R + (size_t)b*(Cdim*HW) + h*Ww + tw + p0;
    float* Xp = X + (size_t)b*(Cdim*HW) + h*Ww + tw + p0;
    #pragma unroll
    for (int oi = 0; oi < 4; oi++){
      int o = o0 + oi;
      float bb = b1[o];
      float4 r4 = *(const float4*)(Rp + (size_t)o*HW);
      float4 out;
      out.x = acc[oi][0] + bb + r4.x;
      out.y = acc[oi][1] + bb + r4.y;
      out.z = acc[oi][2] + bb + r4.z;
      out.w = acc[oi][3] + bb + r4.w;
      *(float4*)(Xp + (size_t)o*HW) = out;
    }
  }
}

// ---------------- WSA stage 1: t = BN(conv1x1(x, pi_w, pi_b)) ----------------
// GEMM: M=64, N=60, K=60. BN applied in epilogue.
__global__ __launch_bounds__(256) void k_wsat(const float* __restrict__ X, float* __restrict__ T,
                                              fp piw, fp pib, fp g, fp bt, fp m, fp v){
  __shared__ __align__(16) float A[60*64];
  __shared__ __align__(16) float Wl[60*64];
  int tid = threadIdx.x;
  int b, h, tw; tile_decode(blockIdx.x, b, h, tw);
  const float* Xb = X + (size_t)b*(Cdim*HW) + h*Ww + tw;
  for (int idx = tid; idx < 60*64; idx += 256){
    int k = idx >> 6, p = idx & 63;
    A[idx] = Xb[k*HW + p];
  }
  for (int idx = tid; idx < 60*60; idx += 256){
    int k = idx / 60, o = idx - k*60;
    Wl[k*64 + o] = piw[o*Cdim + k];
  }
  __syncthreads();
  if (tid < 240){
    int p0 = (tid & 15)*4;
    int o0 = (tid >> 4)*4;
    float acc[4][4];
    #pragma unroll
    for (int oi = 0; oi < 4; oi++)
      #pragma unroll
      for (int pi = 0; pi < 4; pi++) acc[oi][pi] = 0.f;
    #pragma unroll 4
    for (int k = 0; k < 60; k++){
      float4 a4 = *(const float4*)(&A[k*64 + p0]);
      float4 w4 = *(const float4*)(&Wl[k*64 + o0]);
      float av[4] = {a4.x,a4.y,a4.z,a4.w};
      float wv[4] = {w4.x,w4.y,w4.z,w4.w};
      #pragma unroll
      for (int oi = 0; oi < 4; oi++)
        #pragma unroll
        for (int pi = 0; pi < 4; pi++)
          acc[oi][pi] += wv[oi]*av[pi];
    }
    float* Tb = T + (size_t)b*(Cdim*HW) + h*Ww + tw + p0;
    #pragma unroll
    for (int oi = 0; oi < 4; oi++){
      int o = o0 + oi;
      float scale = g[o] * rsqrtf(v[o] + 1e-5f);
      float cns   = (pib[o] - m[o])*scale + bt[o];
      float4 out;
      out.x = acc[oi][0]*scale + cns;
      out.y = acc[oi][1]*scale + cns;
      out.z = acc[oi][2]*scale + cns;
      out.w = acc[oi][3]*scale + cns;
      *(float4*)(Tb + (size_t)o*HW) = out;
    }
  }
}

// ---------------- WSA stage 2: windowed attention, 4x4 register tiles (unchanged) ----------------
__global__ __launch_bounds__(256) void k_attn(const float* __restrict__ T, float* __restrict__ Y,
                                              fp mw, fp mb){
  __shared__ __align__(16) float R1[64*68]; // sub[k*68+p], later V[tok*68+c]
  __shared__ __align__(16) float R2[64*68]; // mwT[k*68+c], later St[q*68+p]
  __shared__ __align__(16) float R3[60*64]; // Qt[c*64+tok]
  int tid = threadIdx.x;
  int blk = blockIdx.x;
  int b = blk >> 10; int ij = blk & 1023; int wi = ij >> 5; int wj = ij & 31;
  const float* Tb = T + (size_t)b*(Cdim*HW);

  for (int idx = tid; idx < Cdim*64; idx += 256){
    int k = idx >> 6, p = idx & 63;
    int u = p >> 3, vq = p & 7;
    int r  = wi*8 + 2*vq; if (r > 255) r -= 8;
    int cc = wj*8 + 2*u;  if (cc > 255) cc -= 8;
    R1[k*68 + p] = Tb[k*HW + r*Ww + cc];
  }
  for (int idx = tid; idx < Cdim*Cdim; idx += 256){
    int k = idx / Cdim, c = idx - k*Cdim;
    R2[k*68 + c] = mw[c*Cdim + k];
  }
  __syncthreads();

  if (tid < 240){
    int p0 = (tid & 15)*4, c0 = (tid >> 4)*4;
    float4 mb4 = *(const float4*)(mb + c0);
    float bias[4] = {mb4.x, mb4.y, mb4.z, mb4.w};
    float acc[4][4];
    #pragma unroll
    for (int ci = 0; ci < 4; ci++)
      #pragma unroll
      for (int pi = 0; pi < 4; pi++) acc[ci][pi] = bias[ci];
    #pragma unroll 4
    for (int k = 0; k < Cdim; k++){
      float4 A  = *(const float4*)(&R1[k*68 + p0]);
      float4 Bv = *(const float4*)(&R2[k*68 + c0]);
      float Af[4] = {A.x, A.y, A.z, A.w};
      float Bf[4] = {Bv.x, Bv.y, Bv.z, Bv.w};
      #pragma unroll
      for (int ci = 0; ci < 4; ci++)
        #pragma unroll
        for (int pi = 0; pi < 4; pi++)
          acc[ci][pi] += Bf[ci]*Af[pi];
    }
    #pragma unroll
    for (int ci = 0; ci < 4; ci++)
      *(float4*)(&R3[(c0+ci)*64 + p0]) = make_float4(acc[ci][0], acc[ci][1], acc[ci][2], acc[ci][3]);
  }
  __syncthreads();

  {
    int p = tid & 63; int cg = tid >> 6;
    int pr = p >> 3, pc = p & 7;
    const float* base = Tb + (wi*8+pr)*Ww + (wj*8+pc);
    #pragma unroll
    for (int t2 = 0; t2 < 15; t2++)
      R1[p*68 + cg*15 + t2] = base[(cg*15+t2)*HW];
  }
  if (tid < 64){
    R1[tid*68 + 60] = 0.f; R1[tid*68 + 61] = 0.f;
    R1[tid*68 + 62] = 0.f; R1[tid*68 + 63] = 0.f;
  }
  {
    int p0 = (tid & 15)*4, q0 = (tid >> 4)*4;
    float acc[4][4];
    #pragma unroll
    for (int qi = 0; qi < 4; qi++)
      #pragma unroll
      for (int pi = 0; pi < 4; pi++) acc[qi][pi] = 0.f;
    #pragma unroll 4
    for (int c = 0; c < Cdim; c++){
      float4 A  = *(const float4*)(&R3[c*64 + p0]);
      float4 Bv = *(const float4*)(&R3[c*64 + q0]);
      float Af[4] = {A.x, A.y, A.z, A.w};
      float Bf[4] = {Bv.x, Bv.y, Bv.z, Bv.w};
      #pragma unroll
      for (int qi = 0; qi < 4; qi++)
        #pragma unroll
        for (int pi = 0; pi < 4; pi++)
          acc[qi][pi] += Bf[qi]*Af[pi];
    }
    __syncthreads();
    #pragma unroll
    for (int qi = 0; qi < 4; qi++)
      *(float4*)(&R2[(q0+qi)*68 + p0]) = make_float4(acc[qi][0], acc[qi][1], acc[qi][2], acc[qi][3]);
  }
  __syncthreads();

  if (tid < 64){
    int p = tid;
    float mx = -1e30f;
    #pragma unroll
    for (int q = 0; q < 64; q++) mx = fmaxf(mx, R2[q*68 + p]);
    float sum = 0.f;
    #pragma unroll
    for (int q = 0; q < 64; q++){
      float e = __expf(R2[q*68 + p] - mx);
      R2[q*68 + p] = e; sum += e;
    }
    float inv = 1.f/sum;
    #pragma unroll
    for (int q = 0; q < 64; q++) R2[q*68 + p] *= inv;
  }
  __syncthreads();

  {
    int p0 = (tid & 15)*4, c0 = (tid >> 4)*4;
    float acc[4][4];
    #pragma unroll
    for (int ci = 0; ci < 4; ci++)
      #pragma unroll
      for (int pi = 0; pi < 4; pi++) acc[ci][pi] = 0.f;
    #pragma unroll 4
    for (int q = 0; q < 64; q++){
      float4 S4 = *(const float4*)(&R2[q*68 + p0]);
      float4 V4 = *(const float4*)(&R1[q*68 + c0]);
      float Sf[4] = {S4.x, S4.y, S4.z, S4.w};
      float Vf[4] = {V4.x, V4.y, V4.z, V4.w};
      #pragma unroll
      for (int ci = 0; ci < 4; ci++)
        #pragma unroll
        for (int pi = 0; pi < 4; pi++)
          acc[ci][pi] += Sf[pi]*Vf[ci];
    }
    float* Yb = Y + (size_t)b*(Cdim*HW);
    #pragma unroll
    for (int ci = 0; ci < 4; ci++){
      int c = c0 + ci;
      if (c < Cdim){
        #pragma unroll
        for (int pi = 0; pi < 4; pi++){
          int p = p0 + pi;
          Yb[c*HW + (wi*8 + (p>>3))*Ww + wj*8 + (p&7)] = acc[ci][pi];
        }
      }
    }
  }
}

// ---------------- WSA stage 3: X = conv1x1(y, po) + X ----------------
__global__ __launch_bounds__(256) void k_wsaout(const float* __restrict__ Y, float* __restrict__ X,
                                                fp pw, fp pb){
  __shared__ __align__(16) float A[60*64];
  __shared__ __align__(16) float Wl[60*64];
  int tid = threadIdx.x;
  int b, h, tw; tile_decode(blockIdx.x, b, h, tw);
  const float* Yb = Y + (size_t)b*(Cdim*HW) + h*Ww + tw;
  for (int idx = tid; idx < 60*64; idx += 256){
    int k = idx >> 6, p = idx & 63;
    A[idx] = Yb[k*HW + p];
  }
  for (int idx = tid; idx < 60*60; idx += 256){
    int k = idx / 60, o = idx - k*60;
    Wl[k*64 + o] = pw[o*Cdim + k];
  }
  __syncthreads();
  if (tid < 240){
    int p0 = (tid & 15)*4;
    int o0 = (tid >> 4)*4;
    float acc[4][4];
    #pragma unroll
    for (int oi = 0; oi < 4; oi++)
      #pragma unroll
      for (int pi = 0; pi < 4; pi++) acc[oi][pi] = 0.f;
    #pragma unroll 4
    for (int k = 0; k < 60; k++){
      float4 a4 = *(const float4*)(&A[k*64 + p0]);
      float4 w4 = *(const float4*)(&Wl[k*64 + o0]);
      float av[4] = {a4.x,a4.y,a4.z,a4.w};
      float wv[4] = {w4.x,w4.y,w4.z,w4.w};
      #pragma unroll
      for (int oi = 0; oi < 4; oi++)
        #pragma unroll
        for (int pi = 0; pi < 4; pi++)
          acc[oi][pi] += wv[oi]*av[pi];
    }
    float* Xp = X + (size_t)b*(Cdim*HW) + h*Ww + tw + p0;
    #pragma unroll
    for (int oi = 0; oi < 4; oi++){
      int o = o0 + oi;
      float bb = pb[o];
      float4 r4 = *(const float4*)(Xp + (size_t)o*HW);
      float4 out;
      out.x = acc[oi][0] + bb + r4.x;
      out.y = acc[oi][1] + bb + r4.y;
      out.z = acc[oi][2] + bb + r4.z;
      out.w = acc[oi][3] + bb + r4.w;
      *(float4*)(Xp + (size_t)o*HW) = out;
    }
  }
}

extern "C" void kernel_launch(void* const* d_in, const int* in_sizes, int n_in,
                              void* d_out, int out_size, void* d_ws, size_t ws_size,
                              hipStream_t stream){
  fp x      = (fp)d_in[0];
  fp lfe_w0 = (fp)d_in[1];
  fp lfe_b0 = (fp)d_in[2];
  fp lfe_w1 = (fp)d_in[3];
  fp lfe_b1 = (fp)d_in[4];
  fp pi_w   = (fp)d_in[5];
  fp pi_b   = (fp)d_in[6];
  fp bn_g   = (fp)d_in[7];
  fp bn_b   = (fp)d_in[8];
  fp bn_m   = (fp)d_in[9];
  fp bn_v   = (fp)d_in[10];
  fp mask_w = (fp)d_in[11];
  fp mask_b = (fp)d_in[12];
  fp po_w   = (fp)d_in[13];
  fp po_b   = (fp)d_in[14];

  const size_t XSZ = (size_t)Bn*Cdim*HW;     // 15,728,640 floats (63 MB)
  float* X  = (float*)d_out;                 // residual stream lives in d_out (fp32)
  float* Y1 = (float*)d_ws;                  // [0, 2*XSZ): 120-ch LFE intermediate
  float* T  = Y1;                            // [0, XSZ): t-tensor (Y1 dead by then)
  float* Yw = Y1 + XSZ;                      // [XSZ, 2*XSZ): attention output

  const int NT = NPIX/64;                    // 4096 64-px tiles

  for (int d = 0; d < 2; d++){
    fp src = (d == 0) ? x : X;               // depth-0 reads the input directly
    k_lfe1  <<<NT, 256, 0, stream>>>(src, Y1, lfe_w0 + d*Ce*Cdim, lfe_b0 + d*Ce);
    k_lfe2  <<<NT, 256, 0, stream>>>(Y1, src, X, lfe_w1 + d*Ce*Cdim, lfe_b1 + d*Cdim);
    k_wsat  <<<NT, 256, 0, stream>>>(X, T, pi_w + d*Cdim*Cdim, pi_b + d*Cdim,
                                     bn_g + d*Cdim, bn_b + d*Cdim, bn_m + d*Cdim, bn_v + d*Cdim);
    k_attn  <<<Bn*32*32, 256, 0, stream>>>(T, Yw, mask_w + d*Cdim*Cdim, mask_b + d*Cdim);
    k_wsaout<<<NT, 256, 0, stream>>>(Yw, X, po_w + d*Cdim*Cdim, po_b + d*Cdim);
  }
}

// Round 6
// 1092.327 us; speedup vs baseline: 1.5070x; 1.0213x over previous
//
#include <hip/hip_runtime.h>
#include <math.h>

#define Hh 256
#define Ww 256
#define HW 65536
#define Bn 4
#define Cdim 60
#define Ce 120
#define NPIX (Bn*HW)

typedef const float* fp;

__device__ __forceinline__ float gelu_exact(float x){
  return 0.5f*x*(1.f + erff(x*0.70710678118654752f));
}

// decode 64-px tile id -> (b, h, tw). 1024 tiles/image (256 rows x 4 tiles).
__device__ __forceinline__ void tile_decode(int blk, int& b, int& h, int& tw){
  b = blk >> 10; int rem = blk & 1023; h = rem >> 2; tw = (rem & 3) << 6;
}

// ---------------- LFE stage 1: y1 = gelu(conv1x1(shift(src), w0, b0)) ----------------
// GEMM: M=64 px, N=120 out, K=60. Weights staged NATURAL [o][k] pad-61 (coalesced global,
// conflict-free LDS writes); GEMM reads W via LDS scalar broadcasts, A via b128.
__global__ __launch_bounds__(256) void k_lfe1(const float* __restrict__ X, float* __restrict__ Y1,
                                              fp w0, fp b0){
  __shared__ __align__(16) float A[60*64];     // shifted input [k][p]
  __shared__ __align__(16) float Wn[120*61];   // natural weights [o][k], pad 61
  int tid = threadIdx.x;
  int b, h, tw; tile_decode(blockIdx.x, b, h, tw);
  const float* Xb = X + (size_t)b*(Cdim*HW);
  for (int idx = tid; idx < 60*64; idx += 256){
    int k = idx >> 6, p = idx & 63;
    int grp = k / 12;
    int hh = h, ww = tw + p; bool ok = true;
    if (grp == 0){ ww += 1; ok = (ww < Ww); }
    else if (grp == 1){ ww -= 1; ok = (ww >= 0); }
    else if (grp == 2){ hh = h+1; ok = (hh < Hh); }
    else if (grp == 3){ hh = h-1; ok = (hh >= 0); }
    A[idx] = ok ? Xb[k*HW + hh*Ww + ww] : 0.f;
  }
  for (int idx = tid; idx < 120*60; idx += 256){   // coalesced read, conflict-free write
    int o = idx / 60, k = idx - o*60;
    Wn[o*61 + k] = w0[idx];
  }
  __syncthreads();
  if (tid < 240){
    int p0 = (tid & 15)*4;
    int o0 = (tid >> 4)*8;
    float acc[8][4];
    #pragma unroll
    for (int oi = 0; oi < 8; oi++){
      float bb = b0[o0+oi];
      #pragma unroll
      for (int pi = 0; pi < 4; pi++) acc[oi][pi] = bb;
    }
    #pragma unroll 4
    for (int k = 0; k < 60; k++){
      float4 a4 = *(const float4*)(&A[k*64 + p0]);
      float av[4] = {a4.x,a4.y,a4.z,a4.w};
      #pragma unroll
      for (int oi = 0; oi < 8; oi++){
        float wv = Wn[(o0+oi)*61 + k];           // broadcast: 4 distinct addrs/wave, distinct banks
        #pragma unroll
        for (int pi = 0; pi < 4; pi++)
          acc[oi][pi] += wv*av[pi];
      }
    }
    float* Yb = Y1 + (size_t)b*(Ce*HW) + h*Ww + tw + p0;
    #pragma unroll
    for (int oi = 0; oi < 8; oi++){
      float4 r;
      r.x = gelu_exact(acc[oi][0]); r.y = gelu_exact(acc[oi][1]);
      r.z = gelu_exact(acc[oi][2]); r.w = gelu_exact(acc[oi][3]);
      *(float4*)(Yb + (size_t)(o0+oi)*HW) = r;
    }
  }
}

// ---------------- LFE stage 2: X = conv1x1(shift(y1), w1, b1) + resid ----------------
// GEMM: M=64, N=60, K=120 (A staged in two 60-row halves). W natural [c][e] pad-121.
__global__ __launch_bounds__(256) void k_lfe2(const float* __restrict__ Y1,
                                              const float* __restrict__ R,
                                              float* __restrict__ X,
                                              fp w1, fp b1){
  __shared__ __align__(16) float A[60*64];
  __shared__ __align__(16) float Wn[60*121];   // natural [c][e], pad 121
  int tid = threadIdx.x;
  int b, h, tw; tile_decode(blockIdx.x, b, h, tw);
  const float* Yb = Y1 + (size_t)b*(Ce*HW);
  for (int idx = tid; idx < 60*120; idx += 256){
    int c = idx / 120, e = idx - c*120;
    Wn[c*121 + e] = w1[idx];
  }
  int p0 = (tid & 15)*4;
  int o0 = (tid >> 4)*4;
  float acc[4][4];
  #pragma unroll
  for (int oi = 0; oi < 4; oi++)
    #pragma unroll
    for (int pi = 0; pi < 4; pi++) acc[oi][pi] = 0.f;
  #pragma unroll 1
  for (int half = 0; half < 2; half++){
    __syncthreads();                            // W ready / previous half's GEMM reads done
    for (int idx = tid; idx < 60*64; idx += 256){
      int k = idx >> 6, p = idx & 63;
      int e = half*60 + k;
      int grp = e / 24;
      int hh = h, ww = tw + p; bool ok = true;
      if (grp == 0){ ww += 1; ok = (ww < Ww); }
      else if (grp == 1){ ww -= 1; ok = (ww >= 0); }
      else if (grp == 2){ hh = h+1; ok = (hh < Hh); }
      else if (grp == 3){ hh = h-1; ok = (hh >= 0); }
      A[idx] = ok ? Yb[e*HW + hh*Ww + ww] : 0.f;
    }
    __syncthreads();
    if (tid < 240){
      #pragma unroll 4
      for (int k = 0; k < 60; k++){
        float4 a4 = *(const float4*)(&A[k*64 + p0]);
        float av[4] = {a4.x,a4.y,a4.z,a4.w};
        #pragma unroll
        for (int oi = 0; oi < 4; oi++){
          float wv = Wn[(o0+oi)*121 + half*60 + k];
          #pragma unroll
          for (int pi = 0; pi < 4; pi++)
            acc[oi][pi] += wv*av[pi];
        }
      }
    }
  }
  if (tid < 240){
    const float* Rp = R + (size_t)b*(Cdim*HW) + h*Ww + tw + p0;
    float* Xp = X + (size_t)b*(Cdim*HW) + h*Ww + tw + p0;
    #pragma unroll
    for (int oi = 0; oi < 4; oi++){
      int o = o0 + oi;
      float bb = b1[o];
      float4 r4 = *(const float4*)(Rp + (size_t)o*HW);
      float4 out;
      out.x = acc[oi][0] + bb + r4.x;
      out.y = acc[oi][1] + bb + r4.y;
      out.z = acc[oi][2] + bb + r4.z;
      out.w = acc[oi][3] + bb + r4.w;
      *(float4*)(Xp + (size_t)o*HW) = out;
    }
  }
}

// ---------------- WSA stage 1: t = BN(conv1x1(x, pi_w, pi_b)) ----------------
// GEMM: M=64, N=60, K=60. W natural [o][k] pad-61 with BN scale folded at staging.
__global__ __launch_bounds__(256) void k_wsat(const float* __restrict__ X, float* __restrict__ T,
                                              fp piw, fp pib, fp g, fp bt, fp m, fp v){
  __shared__ __align__(16) float A[60*64];
  __shared__ __align__(16) float Wn[60*61];
  int tid = threadIdx.x;
  int b, h, tw; tile_decode(blockIdx.x, b, h, tw);
  const float* Xb = X + (size_t)b*(Cdim*HW) + h*Ww + tw;
  for (int idx = tid; idx < 60*64; idx += 256){
    int k = idx >> 6, p = idx & 63;
    A[idx] = Xb[k*HW + p];
  }
  for (int idx = tid; idx < 60*60; idx += 256){
    int o = idx / 60, k = idx - o*60;
    float scale = g[o] * rsqrtf(v[o] + 1e-5f);
    Wn[o*61 + k] = piw[idx] * scale;
  }
  __syncthreads();
  if (tid < 240){
    int p0 = (tid & 15)*4;
    int o0 = (tid >> 4)*4;
    float acc[4][4];
    #pragma unroll
    for (int oi = 0; oi < 4; oi++)
      #pragma unroll
      for (int pi = 0; pi < 4; pi++) acc[oi][pi] = 0.f;
    #pragma unroll 4
    for (int k = 0; k < 60; k++){
      float4 a4 = *(const float4*)(&A[k*64 + p0]);
      float av[4] = {a4.x,a4.y,a4.z,a4.w};
      #pragma unroll
      for (int oi = 0; oi < 4; oi++){
        float wv = Wn[(o0+oi)*61 + k];
        #pragma unroll
        for (int pi = 0; pi < 4; pi++)
          acc[oi][pi] += wv*av[pi];
      }
    }
    float* Tb = T + (size_t)b*(Cdim*HW) + h*Ww + tw + p0;
    #pragma unroll
    for (int oi = 0; oi < 4; oi++){
      int o = o0 + oi;
      float scale = g[o] * rsqrtf(v[o] + 1e-5f);
      float cns   = (pib[o] - m[o])*scale + bt[o];
      float4 out;
      out.x = acc[oi][0] + cns;
      out.y = acc[oi][1] + cns;
      out.z = acc[oi][2] + cns;
      out.w = acc[oi][3] + cns;
      *(float4*)(Tb + (size_t)o*HW) = out;
    }
  }
}

// ---------------- WSA stage 2: windowed attention ----------------
// mask_w staged NATURAL [c][k] pad-61 into R2 (overwritten by scores after barrier).
__global__ __launch_bounds__(256) void k_attn(const float* __restrict__ T, float* __restrict__ Y,
                                              fp mw, fp mb){
  __shared__ __align__(16) float R1[64*68]; // sub[k*68+p], later V[tok*68+c]
  __shared__ __align__(16) float R2[64*68]; // Wn[c*61+k] (mask_w), later St[q*68+p]
  __shared__ __align__(16) float R3[60*64]; // Qt[c*64+tok]
  int tid = threadIdx.x;
  int blk = blockIdx.x;
  int b = blk >> 10; int ij = blk & 1023; int wi = ij >> 5; int wj = ij & 31;
  const float* Tb = T + (size_t)b*(Cdim*HW);

  for (int idx = tid; idx < Cdim*64; idx += 256){
    int k = idx >> 6, p = idx & 63;
    int u = p >> 3, vq = p & 7;
    int r  = wi*8 + 2*vq; if (r > 255) r -= 8;
    int cc = wj*8 + 2*u;  if (cc > 255) cc -= 8;
    R1[k*68 + p] = Tb[k*HW + r*Ww + cc];
  }
  for (int idx = tid; idx < Cdim*Cdim; idx += 256){   // coalesced, natural layout
    int c = idx / Cdim, k = idx - c*Cdim;
    R2[c*61 + k] = mw[idx];
  }
  __syncthreads();

  // qproj: q[p][c] = sum_k mw[c][k]*sub[k][p] + mb[c]
  if (tid < 240){
    int p0 = (tid & 15)*4, c0 = (tid >> 4)*4;
    float4 mb4 = *(const float4*)(mb + c0);
    float bias[4] = {mb4.x, mb4.y, mb4.z, mb4.w};
    float acc[4][4];
    #pragma unroll
    for (int ci = 0; ci < 4; ci++)
      #pragma unroll
      for (int pi = 0; pi < 4; pi++) acc[ci][pi] = bias[ci];
    #pragma unroll 4
    for (int k = 0; k < Cdim; k++){
      float4 a4 = *(const float4*)(&R1[k*68 + p0]);
      float av[4] = {a4.x, a4.y, a4.z, a4.w};
      #pragma unroll
      for (int ci = 0; ci < 4; ci++){
        float wv = R2[(c0+ci)*61 + k];
        #pragma unroll
        for (int pi = 0; pi < 4; pi++)
          acc[ci][pi] += wv*av[pi];
      }
    }
    #pragma unroll
    for (int ci = 0; ci < 4; ci++)
      *(float4*)(&R3[(c0+ci)*64 + p0]) = make_float4(acc[ci][0], acc[ci][1], acc[ci][2], acc[ci][3]);
  }
  __syncthreads();

  // stage V[tok][c] into R1 (sub dead); compute scores from R3
  {
    int p = tid & 63; int cg = tid >> 6;
    int pr = p >> 3, pc = p & 7;
    const float* base = Tb + (wi*8+pr)*Ww + (wj*8+pc);
    #pragma unroll
    for (int t2 = 0; t2 < 15; t2++)
      R1[p*68 + cg*15 + t2] = base[(cg*15+t2)*HW];
  }
  if (tid < 64){
    R1[tid*68 + 60] = 0.f; R1[tid*68 + 61] = 0.f;
    R1[tid*68 + 62] = 0.f; R1[tid*68 + 63] = 0.f;
  }
  {
    int p0 = (tid & 15)*4, q0 = (tid >> 4)*4;
    float acc[4][4];
    #pragma unroll
    for (int qi = 0; qi < 4; qi++)
      #pragma unroll
      for (int pi = 0; pi < 4; pi++) acc[qi][pi] = 0.f;
    #pragma unroll 4
    for (int c = 0; c < Cdim; c++){
      float4 A4 = *(const float4*)(&R3[c*64 + p0]);
      float4 B4 = *(const float4*)(&R3[c*64 + q0]);
      float Af[4] = {A4.x, A4.y, A4.z, A4.w};
      float Bf[4] = {B4.x, B4.y, B4.z, B4.w};
      #pragma unroll
      for (int qi = 0; qi < 4; qi++)
        #pragma unroll
        for (int pi = 0; pi < 4; pi++)
          acc[qi][pi] += Bf[qi]*Af[pi];
    }
    __syncthreads();   // qproj reads of R2 (Wn) done; V-stage R1 writes done
    #pragma unroll
    for (int qi = 0; qi < 4; qi++)
      *(float4*)(&R2[(q0+qi)*68 + p0]) = make_float4(acc[qi][0], acc[qi][1], acc[qi][2], acc[qi][3]);
  }
  __syncthreads();

  if (tid < 64){
    int p = tid;
    float mx = -1e30f;
    #pragma unroll
    for (int q = 0; q < 64; q++) mx = fmaxf(mx, R2[q*68 + p]);
    float sum = 0.f;
    #pragma unroll
    for (int q = 0; q < 64; q++){
      float e = __expf(R2[q*68 + p] - mx);
      R2[q*68 + p] = e; sum += e;
    }
    float inv = 1.f/sum;
    #pragma unroll
    for (int q = 0; q < 64; q++) R2[q*68 + p] *= inv;
  }
  __syncthreads();

  {
    int p0 = (tid & 15)*4, c0 = (tid >> 4)*4;
    float acc[4][4];
    #pragma unroll
    for (int ci = 0; ci < 4; ci++)
      #pragma unroll
      for (int pi = 0; pi < 4; pi++) acc[ci][pi] = 0.f;
    #pragma unroll 4
    for (int q = 0; q < 64; q++){
      float4 S4 = *(const float4*)(&R2[q*68 + p0]);
      float4 V4 = *(const float4*)(&R1[q*68 + c0]);
      float Sf[4] = {S4.x, S4.y, S4.z, S4.w};
      float Vf[4] = {V4.x, V4.y, V4.z, V4.w};
      #pragma unroll
      for (int ci = 0; ci < 4; ci++)
        #pragma unroll
        for (int pi = 0; pi < 4; pi++)
          acc[ci][pi] += Sf[pi]*Vf[ci];
    }
    float* Yb = Y + (size_t)b*(Cdim*HW);
    #pragma unroll
    for (int ci = 0; ci < 4; ci++){
      int c = c0 + ci;
      if (c < Cdim){
        #pragma unroll
        for (int pi = 0; pi < 4; pi++){
          int p = p0 + pi;
          Yb[c*HW + (wi*8 + (p>>3))*Ww + wj*8 + (p&7)] = acc[ci][pi];
        }
      }
    }
  }
}

// ---------------- WSA stage 3: X = conv1x1(y, po) + X ----------------
__global__ __launch_bounds__(256) void k_wsaout(const float* __restrict__ Y, float* __restrict__ X,
                                                fp pw, fp pb){
  __shared__ __align__(16) float A[60*64];
  __shared__ __align__(16) float Wn[60*61];
  int tid = threadIdx.x;
  int b, h, tw; tile_decode(blockIdx.x, b, h, tw);
  const float* Yb = Y + (size_t)b*(Cdim*HW) + h*Ww + tw;
  for (int idx = tid; idx < 60*64; idx += 256){
    int k = idx >> 6, p = idx & 63;
    A[idx] = Yb[k*HW + p];
  }
  for (int idx = tid; idx < 60*60; idx += 256){
    int o = idx / 60, k = idx - o*60;
    Wn[o*61 + k] = pw[idx];
  }
  __syncthreads();
  if (tid < 240){
    int p0 = (tid & 15)*4;
    int o0 = (tid >> 4)*4;
    float acc[4][4];
    #pragma unroll
    for (int oi = 0; oi < 4; oi++)
      #pragma unroll
      for (int pi = 0; pi < 4; pi++) acc[oi][pi] = 0.f;
    #pragma unroll 4
    for (int k = 0; k < 60; k++){
      float4 a4 = *(const float4*)(&A[k*64 + p0]);
      float av[4] = {a4.x,a4.y,a4.z,a4.w};
      #pragma unroll
      for (int oi = 0; oi < 4; oi++){
        float wv = Wn[(o0+oi)*61 + k];
        #pragma unroll
        for (int pi = 0; pi < 4; pi++)
          acc[oi][pi] += wv*av[pi];
      }
    }
    float* Xp = X + (size_t)b*(Cdim*HW) + h*Ww + tw + p0;
    #pragma unroll
    for (int oi = 0; oi < 4; oi++){
      int o = o0 + oi;
      float bb = pb[o];
      float4 r4 = *(const float4*)(Xp + (size_t)o*HW);
      float4 out;
      out.x = acc[oi][0] + bb + r4.x;
      out.y = acc[oi][1] + bb + r4.y;
      out.z = acc[oi][2] + bb + r4.z;
      out.w = acc[oi][3] + bb + r4.w;
      *(float4*)(Xp + (size_t)o*HW) = out;
    }
  }
}

extern "C" void kernel_launch(void* const* d_in, const int* in_sizes, int n_in,
                              void* d_out, int out_size, void* d_ws, size_t ws_size,
                              hipStream_t stream){
  fp x      = (fp)d_in[0];
  fp lfe_w0 = (fp)d_in[1];
  fp lfe_b0 = (fp)d_in[2];
  fp lfe_w1 = (fp)d_in[3];
  fp lfe_b1 = (fp)d_in[4];
  fp pi_w   = (fp)d_in[5];
  fp pi_b   = (fp)d_in[6];
  fp bn_g   = (fp)d_in[7];
  fp bn_b   = (fp)d_in[8];
  fp bn_m   = (fp)d_in[9];
  fp bn_v   = (fp)d_in[10];
  fp mask_w = (fp)d_in[11];
  fp mask_b = (fp)d_in[12];
  fp po_w   = (fp)d_in[13];
  fp po_b   = (fp)d_in[14];

  const size_t XSZ = (size_t)Bn*Cdim*HW;     // 15,728,640 floats (63 MB)
  float* X  = (float*)d_out;                 // residual stream lives in d_out (fp32)
  float* Y1 = (float*)d_ws;                  // [0, 2*XSZ): 120-ch LFE intermediate
  float* T  = Y1;                            // [0, XSZ): t-tensor (Y1 dead by then)
  float* Yw = Y1 + XSZ;                      // [XSZ, 2*XSZ): attention output

  const int NT = NPIX/64;                    // 4096 64-px tiles

  for (int d = 0; d < 2; d++){
    fp src = (d == 0) ? x : X;               // depth-0 reads the input directly
    k_lfe1  <<<NT, 256, 0, stream>>>(src, Y1, lfe_w0 + d*Ce*Cdim, lfe_b0 + d*Ce);
    k_lfe2  <<<NT, 256, 0, stream>>>(Y1, src, X, lfe_w1 + d*Ce*Cdim, lfe_b1 + d*Cdim);
    k_wsat  <<<NT, 256, 0, stream>>>(X, T, pi_w + d*Cdim*Cdim, pi_b + d*Cdim,
                                     bn_g + d*Cdim, bn_b + d*Cdim, bn_m + d*Cdim, bn_v + d*Cdim);
    k_attn  <<<Bn*32*32, 256, 0, stream>>>(T, Yw, mask_w + d*Cdim*Cdim, mask_b + d*Cdim);
    k_wsaout<<<NT, 256, 0, stream>>>(Yw, X, po_w + d*Cdim*Cdim, po_b + d*Cdim);
  }
}